// Round 5
// baseline (1143.745 us; speedup 1.0000x reference)
//
#include <hip/hip_runtime.h>
#include <hip/hip_bf16.h>

#define M_TOK 8192
#define IN_F  1024
#define OUT_F 1024
#define N_EXP 8
#define KT    8192   // fused K dimension: 8 experts x 1024

typedef __attribute__((ext_vector_type(8))) _Float16 f16x8;
typedef __attribute__((ext_vector_type(4))) _Float16 f16x4;
typedef __attribute__((ext_vector_type(4))) float    f32x4;

// ---- prep: gate softmax, x -> f16, and out init with gate-weighted bias ----
__global__ void moe_prep_kernel(const float* __restrict__ x, const float* __restrict__ Wg,
                                const float* __restrict__ bg, const float* __restrict__ be,
                                float* __restrict__ g, _Float16* __restrict__ xh,
                                float* __restrict__ out) {
    int token = blockIdx.x * 4 + (threadIdx.x >> 6);
    int lane  = threadIdx.x & 63;
    const float* xr = x + (size_t)token * IN_F;
    float4 xv[4];
    float acc[8] = {0.f,0.f,0.f,0.f,0.f,0.f,0.f,0.f};
#pragma unroll
    for (int kc = 0; kc < 4; ++kc) {
        int i = kc * 256 + lane * 4;
        xv[kc] = *(const float4*)(xr + i);
        float xj[4] = {xv[kc].x, xv[kc].y, xv[kc].z, xv[kc].w};
#pragma unroll
        for (int j = 0; j < 4; ++j) {
            const float4* wr = (const float4*)(Wg + (size_t)(i + j) * 8);
            float4 w0 = wr[0], w1 = wr[1];
            acc[0] = fmaf(xj[j], w0.x, acc[0]); acc[1] = fmaf(xj[j], w0.y, acc[1]);
            acc[2] = fmaf(xj[j], w0.z, acc[2]); acc[3] = fmaf(xj[j], w0.w, acc[3]);
            acc[4] = fmaf(xj[j], w1.x, acc[4]); acc[5] = fmaf(xj[j], w1.y, acc[5]);
            acc[6] = fmaf(xj[j], w1.z, acc[6]); acc[7] = fmaf(xj[j], w1.w, acc[7]);
        }
    }
#pragma unroll
    for (int e = 0; e < 8; ++e) {
        float v = acc[e];
#pragma unroll
        for (int off = 32; off > 0; off >>= 1) v += __shfl_xor(v, off, 64);
        acc[e] = v + bg[e];
    }
    float mx = acc[0];
#pragma unroll
    for (int e = 1; e < 8; ++e) mx = fmaxf(mx, acc[e]);
    float sum = 0.f;
#pragma unroll
    for (int e = 0; e < 8; ++e) { acc[e] = __expf(acc[e] - mx); sum += acc[e]; }
    float inv = 1.0f / sum;
#pragma unroll
    for (int e = 0; e < 8; ++e) acc[e] *= inv;
    if (lane == 0) {
        float4 p0 = {acc[0], acc[1], acc[2], acc[3]};
        float4 p1 = {acc[4], acc[5], acc[6], acc[7]};
        float4* gp = (float4*)(g + (size_t)token * 8);
        gp[0] = p0; gp[1] = p1;
    }
    // x -> f16
    _Float16* xhr = xh + (size_t)token * IN_F;
#pragma unroll
    for (int kc = 0; kc < 4; ++kc) {
        f16x4 h = { (_Float16)xv[kc].x, (_Float16)xv[kc].y,
                    (_Float16)xv[kc].z, (_Float16)xv[kc].w };
        *(f16x4*)(xhr + kc * 256 + lane * 4) = h;
    }
    // out[token][:] = sum_e g_e * be[e][:]
    const float4* be4 = (const float4*)be;
    float4* orow = (float4*)out + (size_t)token * 256;
#pragma unroll
    for (int oc = 0; oc < 4; ++oc) {
        int col4 = oc * 64 + lane;
        float4 a = {0.f, 0.f, 0.f, 0.f};
#pragma unroll
        for (int e = 0; e < 8; ++e) {
            float ge = acc[e];
            float4 b = be4[e * 256 + col4];
            a.x = fmaf(ge, b.x, a.x); a.y = fmaf(ge, b.y, a.y);
            a.z = fmaf(ge, b.z, a.z); a.w = fmaf(ge, b.w, a.w);
        }
        orow[col4] = a;
    }
}

// ---- We [e][i][o] fp32 -> wt2 [o][e*1024+i] f16 (stacked B'^T) ----
__global__ void moe_transpose_we_kernel(const float* __restrict__ We, _Float16* __restrict__ wt) {
    __shared__ float t[64][65];
    int e  = blockIdx.z;
    int i0 = blockIdx.x * 64;   // in_f tile
    int o0 = blockIdx.y * 64;   // out_f tile
    const float* src = We + ((size_t)e << 20);
    int oo = threadIdx.x & 63;
    int ib = threadIdx.x >> 6;  // 0..3
#pragma unroll
    for (int r = 0; r < 16; ++r) {
        int i = ib + r * 4;
        t[i][oo] = src[(size_t)(i0 + i) * OUT_F + o0 + oo];
    }
    __syncthreads();
#pragma unroll
    for (int r = 0; r < 16; ++r) {
        int o = ib + r * 4;
        wt[(size_t)(o0 + o) * KT + (size_t)e * 1024 + i0 + oo] = (_Float16)t[oo][o];
    }
}

// ---- fused GEMM: out += sum_e g[:,e] * (xh @ We[e]); gate in-register, XCD-swizzled ----
__device__ __forceinline__ void async16(const void* gp, void* lp) {
    __builtin_amdgcn_global_load_lds((const __attribute__((address_space(1))) void*)gp,
                                     (__attribute__((address_space(3))) void*)lp, 16, 0, 0);
}

__global__ __launch_bounds__(256, 4) void moe_gemm_kernel(
    const _Float16* __restrict__ xh,   // [M][1024] f16
    const _Float16* __restrict__ wt,   // [N][KT] f16  (stacked B'^T)
    const float* __restrict__ g,       // [M][E]
    float* __restrict__ out)           // [M][N] fp32, atomic accumulate (bias pre-init)
{
    __shared__ __align__(16) _Float16 As[128 * 64];
    __shared__ __align__(16) _Float16 Bs[128 * 64];
    __shared__ float gs[8 * 128];      // [e][row] — transposed for conflict-free reads

    const int tid  = threadIdx.x;
    const int lane = tid & 63;
    const int wave = tid >> 6;

    // XCD-aware remap: 8 n-tiles == 8 XCDs (dispatch round-robin id%8). All blocks
    // with the same n-tile land on one XCD -> its 2 MiB wt slice stays L2-resident.
    // z is the next bit so both split-K halves of an m-tile are adjacent in time.
    const int id   = blockIdx.x;
    const size_t n0 = (size_t)(id & 7) * 128;
    const int rest = id >> 3;
    const int z    = rest & 1;                 // experts z*4 .. z*4+3
    const size_t m0 = (size_t)(rest >> 1) * 128;

    {   // gate block, stored transposed [e][row]
        float4 v = ((const float4*)(g + m0 * 8))[tid];
        int row = tid >> 1, e0 = (tid & 1) * 4;
        gs[(e0 + 0) * 128 + row] = v.x;
        gs[(e0 + 1) * 128 + row] = v.y;
        gs[(e0 + 2) * 128 + row] = v.z;
        gs[(e0 + 3) * 128 + row] = v.w;
    }
    __syncthreads();

    // Staging: linear 16B chunk L = j*256 + tid -> LDS row = L>>3, phys c8 = L&7.
    // XOR swizzle baked into the GLOBAL source: logical k-chunk = phys_c8 ^ (row&7).
    const int rb = tid >> 3;                  // row within 32-row group
    const int c8 = (tid & 7) ^ (rb & 7);      // swizzled logical k-chunk
    const _Float16* pA = xh + (m0 + rb) * (size_t)IN_F + c8 * 8;
    const _Float16* pB = wt + (n0 + rb) * (size_t)KT + (size_t)z * 4096 + c8 * 8;
    char* lA = (char*)As + tid * 16;
    char* lB = (char*)Bs + tid * 16;

    // Fragment read addresses (bytes). A[m=lane&15][k=quad*8+j]; phys c8 = c8_logical ^ (row&7)
    const int quad = lane >> 4;
    const int ml   = lane & 15;
    const int wm   = (wave >> 1) * 64;
    const int wn   = (wave & 1) * 64;
    const int raA0 = (wm + ml) * 128 + (((0 * 4 + quad) ^ (lane & 7)) * 16);
    const int raA1 = (wm + ml) * 128 + (((1 * 4 + quad) ^ (lane & 7)) * 16);
    const int raB0 = (wn + ml) * 128 + (((0 * 4 + quad) ^ (lane & 7)) * 16);
    const int raB1 = (wn + ml) * 128 + (((1 * 4 + quad) ^ (lane & 7)) * 16);

    // per-lane gate scalars, f16, for the 4 m-tiles x 4 experts this lane touches
    _Float16 gh[4][4];
#pragma unroll
    for (int eo = 0; eo < 4; ++eo)
#pragma unroll
        for (int t = 0; t < 4; ++t)
            gh[eo][t] = (_Float16)gs[(z * 4 + eo) * 128 + wm + t * 16 + ml];

    f32x4 acc[4][4] = {};

    // kt-outer / expert-inner: A-tile staged ONCE per kt, reused by all 4 experts.
    for (int kt = 0; kt < 16; ++kt) {
        const _Float16* sA = pA + kt * 64;
#pragma unroll
        for (int j = 0; j < 4; ++j) async16(sA + j * 32 * (size_t)IN_F, lA + j * 4096);

#pragma unroll
        for (int eo = 0; eo < 4; ++eo) {
            const _Float16* sB = pB + eo * 1024 + kt * 64;
#pragma unroll
            for (int j = 0; j < 4; ++j) async16(sB + j * 32 * (size_t)KT, lB + j * 4096);
            __syncthreads();   // drains A (first eo) + B stagings
#pragma unroll
            for (int s = 0; s < 2; ++s) {
                const int rA = s ? raA1 : raA0;
                const int rB = s ? raB1 : raB0;
                f16x8 af[4], bf[4];
#pragma unroll
                for (int t = 0; t < 4; ++t) af[t] = *(const f16x8*)((const char*)As + rA + t * 2048);
#pragma unroll
                for (int t = 0; t < 4; ++t) bf[t] = *(const f16x8*)((const char*)Bs + rB + t * 2048);
                // gate-scale A fragments: per-lane scalar splat (v_pk_mul_f16)
#pragma unroll
                for (int t = 0; t < 4; ++t) af[t] = af[t] * gh[eo][t];
#pragma unroll
                for (int i = 0; i < 4; ++i)
#pragma unroll
                    for (int jn = 0; jn < 4; ++jn)
                        acc[i][jn] = __builtin_amdgcn_mfma_f32_16x16x32_f16(af[i], bf[jn], acc[i][jn], 0, 0, 0);
            }
            __syncthreads();   // all waves done reading As/Bs before next staging
        }
    }

    // Epilogue: C/D layout col = lane&15, row = quad*4 + reg. 2-way split-K atomic add.
#pragma unroll
    for (int i = 0; i < 4; ++i) {
        const int rowb = wm + i * 16 + quad * 4;
#pragma unroll
        for (int jn = 0; jn < 4; ++jn) {
            const size_t col = n0 + wn + jn * 16 + ml;
#pragma unroll
            for (int r = 0; r < 4; ++r)
                unsafeAtomicAdd(out + (m0 + rowb + r) * (size_t)OUT_F + col, acc[i][jn][r]);
        }
    }
}

extern "C" void kernel_launch(void* const* d_in, const int* in_sizes, int n_in,
                              void* d_out, int out_size, void* d_ws, size_t ws_size,
                              hipStream_t stream) {
    const float* x  = (const float*)d_in[0];
    const float* We = (const float*)d_in[1];
    const float* be = (const float*)d_in[2];
    const float* Wg = (const float*)d_in[3];
    const float* bg = (const float*)d_in[4];
    float* out = (float*)d_out;

    char* ws = (char*)d_ws;
    float*    g   = (float*)ws;                                  // 256 KB
    _Float16* xh  = (_Float16*)(ws + (1 << 18));                 // 8192*1024*2 = 16 MiB
    _Float16* wt2 = (_Float16*)(ws + (1 << 18) + (1 << 24));     // 1024*8192*2 = 16 MiB
    // total ws needed: ~34 MB

    moe_prep_kernel<<<M_TOK / 4, 256, 0, stream>>>(x, Wg, bg, be, g, xh, out);
    moe_transpose_we_kernel<<<dim3(IN_F / 64, OUT_F / 64, N_EXP), 256, 0, stream>>>(We, wt2);
    moe_gemm_kernel<<<1024, 256, 0, stream>>>(xh, wt2, g, out);
}

// Round 6
// 295.610 us; speedup vs baseline: 3.8691x; 3.8691x over previous
//
#include <hip/hip_runtime.h>
#include <hip/hip_bf16.h>

#define M_TOK 8192
#define IN_F  1024
#define OUT_F 1024
#define N_EXP 8
#define KT    8192   // stacked K: 8 experts x 1024 (B side only)

typedef __attribute__((ext_vector_type(8))) _Float16 f16x8;
typedef __attribute__((ext_vector_type(4))) _Float16 f16x4;
typedef __attribute__((ext_vector_type(4))) float    f32x4;

// ---- fused prep: blocks [0,2048) gate softmax + x->f16 ; [2048,4096) We transpose ----
__global__ void moe_prep_kernel(const float* __restrict__ x, const float* __restrict__ Wg,
                                const float* __restrict__ bg, const float* __restrict__ We,
                                float* __restrict__ g, _Float16* __restrict__ xh,
                                _Float16* __restrict__ wt) {
    __shared__ float t[64][65];
    if (blockIdx.x < 2048) {
        // ---- gate + convert, 4 tokens per block ----
        int token = blockIdx.x * 4 + (threadIdx.x >> 6);
        int lane  = threadIdx.x & 63;
        const float* xr = x + (size_t)token * IN_F;
        float4 xv[4];
        float acc[8] = {0.f,0.f,0.f,0.f,0.f,0.f,0.f,0.f};
#pragma unroll
        for (int kc = 0; kc < 4; ++kc) {
            int i = kc * 256 + lane * 4;
            xv[kc] = *(const float4*)(xr + i);
            float xj[4] = {xv[kc].x, xv[kc].y, xv[kc].z, xv[kc].w};
#pragma unroll
            for (int j = 0; j < 4; ++j) {
                const float4* wr = (const float4*)(Wg + (size_t)(i + j) * 8);
                float4 w0 = wr[0], w1 = wr[1];
                acc[0] = fmaf(xj[j], w0.x, acc[0]); acc[1] = fmaf(xj[j], w0.y, acc[1]);
                acc[2] = fmaf(xj[j], w0.z, acc[2]); acc[3] = fmaf(xj[j], w0.w, acc[3]);
                acc[4] = fmaf(xj[j], w1.x, acc[4]); acc[5] = fmaf(xj[j], w1.y, acc[5]);
                acc[6] = fmaf(xj[j], w1.z, acc[6]); acc[7] = fmaf(xj[j], w1.w, acc[7]);
            }
        }
#pragma unroll
        for (int e = 0; e < 8; ++e) {
            float v = acc[e];
#pragma unroll
            for (int off = 32; off > 0; off >>= 1) v += __shfl_xor(v, off, 64);
            acc[e] = v + bg[e];
        }
        float mx = acc[0];
#pragma unroll
        for (int e = 1; e < 8; ++e) mx = fmaxf(mx, acc[e]);
        float sum = 0.f;
#pragma unroll
        for (int e = 0; e < 8; ++e) { acc[e] = __expf(acc[e] - mx); sum += acc[e]; }
        float inv = 1.0f / sum;
#pragma unroll
        for (int e = 0; e < 8; ++e) acc[e] *= inv;
        if (lane == 0) {
            float4 p0 = {acc[0], acc[1], acc[2], acc[3]};
            float4 p1 = {acc[4], acc[5], acc[6], acc[7]};
            float4* gp = (float4*)(g + (size_t)token * 8);
            gp[0] = p0; gp[1] = p1;
        }
        _Float16* xhr = xh + (size_t)token * IN_F;
#pragma unroll
        for (int kc = 0; kc < 4; ++kc) {
            f16x4 h = { (_Float16)xv[kc].x, (_Float16)xv[kc].y,
                        (_Float16)xv[kc].z, (_Float16)xv[kc].w };
            *(f16x4*)(xhr + kc * 256 + lane * 4) = h;
        }
    } else {
        // ---- We [e][i][o] fp32 -> wt [o][e*1024+i] f16 (stacked B'^T) ----
        int bid = blockIdx.x - 2048;
        int e  = bid >> 8;
        int o0 = ((bid >> 4) & 15) * 64;
        int i0 = (bid & 15) * 64;
        const float* src = We + ((size_t)e << 20);
        int oo = threadIdx.x & 63;
        int ib = threadIdx.x >> 6;  // 0..3
#pragma unroll
        for (int r = 0; r < 16; ++r) {
            int i = ib + r * 4;
            t[i][oo] = src[(size_t)(i0 + i) * OUT_F + o0 + oo];
        }
        __syncthreads();
#pragma unroll
        for (int r = 0; r < 16; ++r) {
            int o = ib + r * 4;
            wt[(size_t)(o0 + o) * KT + (size_t)e * 1024 + i0 + oo] = (_Float16)t[oo][o];
        }
    }
}

// ---- fused GEMM, no split-K: out = sum_e g[:,e]*(xh@We[e]+be[e]); plain stores ----
__device__ __forceinline__ void async16(const void* gp, void* lp) {
    __builtin_amdgcn_global_load_lds((const __attribute__((address_space(1))) void*)gp,
                                     (__attribute__((address_space(3))) void*)lp, 16, 0, 0);
}

__global__ __launch_bounds__(256, 4) void moe_gemm_kernel(
    const _Float16* __restrict__ xh,   // [M][1024] f16
    const _Float16* __restrict__ wt,   // [N][KT] f16  (stacked B'^T)
    const float* __restrict__ g,       // [M][E]
    const float* __restrict__ be,      // [E][N]
    float* __restrict__ out)           // [M][N] fp32, plain stores
{
    __shared__ __align__(16) _Float16 As[128 * 64];
    __shared__ __align__(16) _Float16 Bs[128 * 64];
    __shared__ float gs[8 * 128];      // gate, transposed [e][row] — conflict-free reads
    __shared__ float bs[8 * 128];      // bias slice [e][col]

    const int tid  = threadIdx.x;
    const int lane = tid & 63;
    const int wave = tid >> 6;
    const size_t n0 = (size_t)blockIdx.x * 128;
    const size_t m0 = (size_t)blockIdx.y * 128;

    {   // gate block -> transposed [e][row]
        float4 v = ((const float4*)(g + m0 * 8))[tid];
        int row = tid >> 1, e0 = (tid & 1) * 4;
        gs[(e0 + 0) * 128 + row] = v.x;
        gs[(e0 + 1) * 128 + row] = v.y;
        gs[(e0 + 2) * 128 + row] = v.z;
        gs[(e0 + 3) * 128 + row] = v.w;
    }
#pragma unroll
    for (int r = 0; r < 4; ++r) {       // bias slice
        int idx = r * 256 + tid;
        int eb = idx >> 7, col = idx & 127;
        bs[idx] = be[(size_t)eb * 1024 + n0 + col];
    }
    __syncthreads();

    // Staging: linear 16B chunk L = j*256 + tid -> LDS row = L>>3, phys c8 = L&7.
    // XOR swizzle baked into the GLOBAL source: logical k-chunk = phys_c8 ^ (row&7).
    const int rb = tid >> 3;
    const int c8 = (tid & 7) ^ (rb & 7);
    const _Float16* pA = xh + (m0 + rb) * (size_t)IN_F + c8 * 8;
    const _Float16* pB = wt + (n0 + rb) * (size_t)KT + c8 * 8;
    char* lA = (char*)As + tid * 16;
    char* lB = (char*)Bs + tid * 16;

    // Fragment read addresses (bytes). A[m=lane&15][k=quad*8+j]; phys c8 = c8_logical ^ (row&7)
    const int quad = lane >> 4;
    const int ml   = lane & 15;
    const int wm   = (wave >> 1) * 64;
    const int wn   = (wave & 1) * 64;
    const int raA0 = (wm + ml) * 128 + (((0 * 4 + quad) ^ (lane & 7)) * 16);
    const int raA1 = (wm + ml) * 128 + (((1 * 4 + quad) ^ (lane & 7)) * 16);
    const int raB0 = (wn + ml) * 128 + (((0 * 4 + quad) ^ (lane & 7)) * 16);
    const int raB1 = (wn + ml) * 128 + (((1 * 4 + quad) ^ (lane & 7)) * 16);

    // acc init = gate-weighted bias: acc[i][jn][r] = sum_e g[row,e]*be[e,col]
    f32x4 acc[4][4] = {};
#pragma unroll
    for (int e = 0; e < 8; ++e) {
        float ge[4][4], bb[4];
#pragma unroll
        for (int i = 0; i < 4; ++i)
#pragma unroll
            for (int r = 0; r < 4; ++r) ge[i][r] = gs[e * 128 + wm + i * 16 + quad * 4 + r];
#pragma unroll
        for (int jn = 0; jn < 4; ++jn) bb[jn] = bs[e * 128 + wn + jn * 16 + ml];
#pragma unroll
        for (int i = 0; i < 4; ++i)
#pragma unroll
            for (int jn = 0; jn < 4; ++jn)
#pragma unroll
                for (int r = 0; r < 4; ++r)
                    acc[i][jn][r] = fmaf(ge[i][r], bb[jn], acc[i][jn][r]);
    }

    // per-lane gate scalars (f16) for the 4 m-tiles x 8 experts this lane touches
    _Float16 gh[8][4];
#pragma unroll
    for (int e = 0; e < 8; ++e)
#pragma unroll
        for (int t = 0; t < 4; ++t)
            gh[e][t] = (_Float16)gs[e * 128 + wm + t * 16 + ml];

    // expert-outer / kt-inner (round-4 proven rhythm: A+B staged per (e,kt), 2 barriers)
    for (int e = 0; e < 8; ++e) {
        const _Float16* pBe = pB + e * 1024;
        for (int kt = 0; kt < 16; ++kt) {
            const _Float16* sA = pA + kt * 64;
            const _Float16* sB = pBe + kt * 64;
#pragma unroll
            for (int j = 0; j < 4; ++j) {
                async16(sA + j * 32 * (size_t)IN_F, lA + j * 4096);
                async16(sB + j * 32 * (size_t)KT,  lB + j * 4096);
            }
            __syncthreads();
#pragma unroll
            for (int s = 0; s < 2; ++s) {
                const int rA = s ? raA1 : raA0;
                const int rB = s ? raB1 : raB0;
                f16x8 af[4], bf[4];
#pragma unroll
                for (int t = 0; t < 4; ++t) af[t] = *(const f16x8*)((const char*)As + rA + t * 2048);
#pragma unroll
                for (int t = 0; t < 4; ++t) bf[t] = *(const f16x8*)((const char*)Bs + rB + t * 2048);
                // gate-scale A fragments: per-lane scalar splat (v_pk_mul_f16)
#pragma unroll
                for (int t = 0; t < 4; ++t) af[t] = af[t] * gh[e][t];
#pragma unroll
                for (int i = 0; i < 4; ++i)
#pragma unroll
                    for (int jn = 0; jn < 4; ++jn)
                        acc[i][jn] = __builtin_amdgcn_mfma_f32_16x16x32_f16(af[i], bf[jn], acc[i][jn], 0, 0, 0);
            }
            __syncthreads();
        }
    }

    // Epilogue: plain coalesced stores. C/D layout col = lane&15, row = quad*4 + reg.
#pragma unroll
    for (int i = 0; i < 4; ++i) {
        const int rowb = wm + i * 16 + quad * 4;
#pragma unroll
        for (int jn = 0; jn < 4; ++jn) {
            const size_t col = n0 + wn + jn * 16 + ml;
#pragma unroll
            for (int r = 0; r < 4; ++r)
                out[(m0 + rowb + r) * (size_t)OUT_F + col] = acc[i][jn][r];
        }
    }
}

extern "C" void kernel_launch(void* const* d_in, const int* in_sizes, int n_in,
                              void* d_out, int out_size, void* d_ws, size_t ws_size,
                              hipStream_t stream) {
    const float* x  = (const float*)d_in[0];
    const float* We = (const float*)d_in[1];
    const float* be = (const float*)d_in[2];
    const float* Wg = (const float*)d_in[3];
    const float* bg = (const float*)d_in[4];
    float* out = (float*)d_out;

    char* ws = (char*)d_ws;
    float*    g   = (float*)ws;                                  // 256 KB
    _Float16* xh  = (_Float16*)(ws + (1 << 18));                 // 8192*1024*2 = 16 MiB
    _Float16* wt2 = (_Float16*)(ws + (1 << 18) + (1 << 24));     // 1024*8192*2 = 16 MiB
    // total ws needed: ~32.3 MB

    moe_prep_kernel<<<4096, 256, 0, stream>>>(x, Wg, bg, We, g, xh, wt2);
    moe_gemm_kernel<<<dim3(OUT_F / 128, M_TOK / 128), 256, 0, stream>>>(xh, wt2, g, be, out);
}

// Round 7
// 256.877 us; speedup vs baseline: 4.4525x; 1.1508x over previous
//
#include <hip/hip_runtime.h>
#include <hip/hip_bf16.h>

#define M_TOK 8192
#define IN_F  1024
#define OUT_F 1024
#define N_EXP 8
#define KT    8192   // stacked K: 8 experts x 1024 (B side only)

typedef __attribute__((ext_vector_type(8))) _Float16 f16x8;
typedef __attribute__((ext_vector_type(4))) _Float16 f16x4;
typedef __attribute__((ext_vector_type(4))) float    f32x4;

// ---- fused prep: blocks [0,2048) gate softmax + x->f16 ; [2048,4096) We transpose ----
__global__ void moe_prep_kernel(const float* __restrict__ x, const float* __restrict__ Wg,
                                const float* __restrict__ bg, const float* __restrict__ We,
                                float* __restrict__ g, _Float16* __restrict__ xh,
                                _Float16* __restrict__ wt) {
    __shared__ float t[64][65];
    if (blockIdx.x < 2048) {
        // ---- gate + convert, 4 tokens per block ----
        int token = blockIdx.x * 4 + (threadIdx.x >> 6);
        int lane  = threadIdx.x & 63;
        const float* xr = x + (size_t)token * IN_F;
        float4 xv[4];
        float acc[8] = {0.f,0.f,0.f,0.f,0.f,0.f,0.f,0.f};
#pragma unroll
        for (int kc = 0; kc < 4; ++kc) {
            int i = kc * 256 + lane * 4;
            xv[kc] = *(const float4*)(xr + i);
            float xj[4] = {xv[kc].x, xv[kc].y, xv[kc].z, xv[kc].w};
#pragma unroll
            for (int j = 0; j < 4; ++j) {
                const float4* wr = (const float4*)(Wg + (size_t)(i + j) * 8);
                float4 w0 = wr[0], w1 = wr[1];
                acc[0] = fmaf(xj[j], w0.x, acc[0]); acc[1] = fmaf(xj[j], w0.y, acc[1]);
                acc[2] = fmaf(xj[j], w0.z, acc[2]); acc[3] = fmaf(xj[j], w0.w, acc[3]);
                acc[4] = fmaf(xj[j], w1.x, acc[4]); acc[5] = fmaf(xj[j], w1.y, acc[5]);
                acc[6] = fmaf(xj[j], w1.z, acc[6]); acc[7] = fmaf(xj[j], w1.w, acc[7]);
            }
        }
#pragma unroll
        for (int e = 0; e < 8; ++e) {
            float v = acc[e];
#pragma unroll
            for (int off = 32; off > 0; off >>= 1) v += __shfl_xor(v, off, 64);
            acc[e] = v + bg[e];
        }
        float mx = acc[0];
#pragma unroll
        for (int e = 1; e < 8; ++e) mx = fmaxf(mx, acc[e]);
        float sum = 0.f;
#pragma unroll
        for (int e = 0; e < 8; ++e) { acc[e] = __expf(acc[e] - mx); sum += acc[e]; }
        float inv = 1.0f / sum;
#pragma unroll
        for (int e = 0; e < 8; ++e) acc[e] *= inv;
        if (lane == 0) {
            float4 p0 = {acc[0], acc[1], acc[2], acc[3]};
            float4 p1 = {acc[4], acc[5], acc[6], acc[7]};
            float4* gp = (float4*)(g + (size_t)token * 8);
            gp[0] = p0; gp[1] = p1;
        }
        _Float16* xhr = xh + (size_t)token * IN_F;
#pragma unroll
        for (int kc = 0; kc < 4; ++kc) {
            f16x4 h = { (_Float16)xv[kc].x, (_Float16)xv[kc].y,
                        (_Float16)xv[kc].z, (_Float16)xv[kc].w };
            *(f16x4*)(xhr + kc * 256 + lane * 4) = h;
        }
    } else {
        // ---- We [e][i][o] fp32 -> wt [o][e*1024+i] f16 (stacked B'^T) ----
        int bid = blockIdx.x - 2048;
        int e  = bid >> 8;
        int o0 = ((bid >> 4) & 15) * 64;
        int i0 = (bid & 15) * 64;
        const float* src = We + ((size_t)e << 20);
        int oo = threadIdx.x & 63;
        int ib = threadIdx.x >> 6;  // 0..3
#pragma unroll
        for (int r = 0; r < 16; ++r) {
            int i = ib + r * 4;
            t[i][oo] = src[(size_t)(i0 + i) * OUT_F + o0 + oo];
        }
        __syncthreads();
#pragma unroll
        for (int r = 0; r < 16; ++r) {
            int o = ib + r * 4;
            wt[(size_t)(o0 + o) * KT + (size_t)e * 1024 + i0 + oo] = (_Float16)t[oo][o];
        }
    }
}

// ---- fused GEMM, no split-K: out = sum_e g[:,e]*(xh@We[e]+be[e]); plain stores ----
__device__ __forceinline__ void async16(const void* gp, void* lp) {
    __builtin_amdgcn_global_load_lds((const __attribute__((address_space(1))) void*)gp,
                                     (__attribute__((address_space(3))) void*)lp, 16, 0, 0);
}

__global__ __launch_bounds__(256, 2) void moe_gemm_kernel(
    const _Float16* __restrict__ xh,   // [M][1024] f16
    const _Float16* __restrict__ wt,   // [N][KT] f16  (stacked B'^T)
    const float* __restrict__ g,       // [M][E]
    const float* __restrict__ be,      // [E][N]
    float* __restrict__ out)           // [M][N] fp32, plain stores
{
    __shared__ __align__(16) _Float16 As[128 * 64];
    __shared__ __align__(16) _Float16 Bs[128 * 64];
    __shared__ float gs[8 * 128];      // gate, transposed [e][row] — conflict-free reads
    __shared__ float bs[8 * 128];      // bias slice [e][col]

    const int tid  = threadIdx.x;
    const int lane = tid & 63;
    const int wave = tid >> 6;
    const size_t n0 = (size_t)blockIdx.x * 128;
    const size_t m0 = (size_t)blockIdx.y * 128;

    {   // gate block -> transposed [e][row]
        float4 v = ((const float4*)(g + m0 * 8))[tid];
        int row = tid >> 1, e0 = (tid & 1) * 4;
        gs[(e0 + 0) * 128 + row] = v.x;
        gs[(e0 + 1) * 128 + row] = v.y;
        gs[(e0 + 2) * 128 + row] = v.z;
        gs[(e0 + 3) * 128 + row] = v.w;
    }
#pragma unroll
    for (int r = 0; r < 4; ++r) {       // bias slice
        int idx = r * 256 + tid;
        int eb = idx >> 7, col = idx & 127;
        bs[idx] = be[(size_t)eb * 1024 + n0 + col];
    }
    __syncthreads();

    // Staging: linear 16B chunk L = j*256 + tid -> LDS row = L>>3, phys c8 = L&7.
    // XOR swizzle baked into the GLOBAL source: logical k-chunk = phys_c8 ^ (row&7).
    const int rb = tid >> 3;
    const int c8 = (tid & 7) ^ (rb & 7);
    const _Float16* pA = xh + (m0 + rb) * (size_t)IN_F + c8 * 8;
    const _Float16* pB = wt + (n0 + rb) * (size_t)KT + c8 * 8;
    char* lA = (char*)As + tid * 16;
    char* lB = (char*)Bs + tid * 16;

    // Fragment read addresses (bytes). A[m=lane&15][k=quad*8+j]; phys c8 = c8_logical ^ (row&7)
    const int quad = lane >> 4;
    const int ml   = lane & 15;
    const int wm   = (wave >> 1) * 64;
    const int wn   = (wave & 1) * 64;
    const int raA0 = (wm + ml) * 128 + (((0 * 4 + quad) ^ (lane & 7)) * 16);
    const int raA1 = (wm + ml) * 128 + (((1 * 4 + quad) ^ (lane & 7)) * 16);
    const int raB0 = (wn + ml) * 128 + (((0 * 4 + quad) ^ (lane & 7)) * 16);
    const int raB1 = (wn + ml) * 128 + (((1 * 4 + quad) ^ (lane & 7)) * 16);

    // acc init = gate-weighted bias: acc[i][jn][r] = sum_e g[row,e]*be[e,col]
    f32x4 acc[4][4] = {};
#pragma unroll
    for (int e = 0; e < 8; ++e) {
        float ge[4][4], bb[4];
#pragma unroll
        for (int i = 0; i < 4; ++i)
#pragma unroll
            for (int r = 0; r < 4; ++r) ge[i][r] = gs[e * 128 + wm + i * 16 + quad * 4 + r];
#pragma unroll
        for (int jn = 0; jn < 4; ++jn) bb[jn] = bs[e * 128 + wn + jn * 16 + ml];
#pragma unroll
        for (int i = 0; i < 4; ++i)
#pragma unroll
            for (int jn = 0; jn < 4; ++jn)
#pragma unroll
                for (int r = 0; r < 4; ++r)
                    acc[i][jn][r] = fmaf(ge[i][r], bb[jn], acc[i][jn][r]);
    }

    // per-lane gate scalars (f16) for the 4 m-tiles x 8 experts this lane touches
    _Float16 gh[8][4];
#pragma unroll
    for (int e = 0; e < 8; ++e)
#pragma unroll
        for (int t = 0; t < 4; ++t)
            gh[e][t] = (_Float16)gs[e * 128 + wm + t * 16 + ml];

    // kt-outer / expert-inner: A-tile staged ONCE per kt (4 async16); B per expert.
    // af fragments are expert-invariant -> load once per kt, scale per expert.
    for (int kt = 0; kt < 16; ++kt) {
        const _Float16* sA = pA + kt * 64;
#pragma unroll
        for (int j = 0; j < 4; ++j) async16(sA + j * 32 * (size_t)IN_F, lA + j * 4096);

        f16x8 afr[2][4];   // raw A fragments for s=0,1 — loaded at e==0, reused across e
#pragma unroll
        for (int e = 0; e < 8; ++e) {
            const _Float16* sB = pB + e * 1024 + kt * 64;
#pragma unroll
            for (int j = 0; j < 4; ++j) async16(sB + j * 32 * (size_t)KT, lB + j * 4096);
            __syncthreads();   // drains A (e==0) + B stagings
            if (e == 0) {
#pragma unroll
                for (int t = 0; t < 4; ++t) {
                    afr[0][t] = *(const f16x8*)((const char*)As + raA0 + t * 2048);
                    afr[1][t] = *(const f16x8*)((const char*)As + raA1 + t * 2048);
                }
            }
#pragma unroll
            for (int s = 0; s < 2; ++s) {
                const int rB = s ? raB1 : raB0;
                f16x8 af[4], bf[4];
#pragma unroll
                for (int t = 0; t < 4; ++t) bf[t] = *(const f16x8*)((const char*)Bs + rB + t * 2048);
                // gate-scale A fragments: per-lane scalar splat (v_pk_mul_f16)
#pragma unroll
                for (int t = 0; t < 4; ++t) af[t] = afr[s][t] * gh[e][t];
#pragma unroll
                for (int i = 0; i < 4; ++i)
#pragma unroll
                    for (int jn = 0; jn < 4; ++jn)
                        acc[i][jn] = __builtin_amdgcn_mfma_f32_16x16x32_f16(af[i], bf[jn], acc[i][jn], 0, 0, 0);
            }
            __syncthreads();   // all waves done with Bs (and As on last e) before restage
        }
    }

    // Epilogue: plain coalesced stores. C/D layout col = lane&15, row = quad*4 + reg.
#pragma unroll
    for (int i = 0; i < 4; ++i) {
        const int rowb = wm + i * 16 + quad * 4;
#pragma unroll
        for (int jn = 0; jn < 4; ++jn) {
            const size_t col = n0 + wn + jn * 16 + ml;
#pragma unroll
            for (int r = 0; r < 4; ++r)
                out[(m0 + rowb + r) * (size_t)OUT_F + col] = acc[i][jn][r];
        }
    }
}

extern "C" void kernel_launch(void* const* d_in, const int* in_sizes, int n_in,
                              void* d_out, int out_size, void* d_ws, size_t ws_size,
                              hipStream_t stream) {
    const float* x  = (const float*)d_in[0];
    const float* We = (const float*)d_in[1];
    const float* be = (const float*)d_in[2];
    const float* Wg = (const float*)d_in[3];
    const float* bg = (const float*)d_in[4];
    float* out = (float*)d_out;

    char* ws = (char*)d_ws;
    float*    g   = (float*)ws;                                  // 256 KB
    _Float16* xh  = (_Float16*)(ws + (1 << 18));                 // 8192*1024*2 = 16 MiB
    _Float16* wt2 = (_Float16*)(ws + (1 << 18) + (1 << 24));     // 1024*8192*2 = 16 MiB
    // total ws needed: ~32.3 MB

    moe_prep_kernel<<<4096, 256, 0, stream>>>(x, Wg, bg, We, g, xh, wt2);
    moe_gemm_kernel<<<dim3(OUT_F / 128, M_TOK / 128), 256, 0, stream>>>(xh, wt2, g, be, out);
}